// Round 14
// baseline (248.016 us; speedup 1.0000x reference)
//
#include <hip/hip_runtime.h>
#include <cstddef>

#define B_ROWS 8192
#define DIM    1024
#define NSESS  32
#define MT     192       // rows per M-tile; balanced split guarantees nrows<=192
#define NTILE  256       // cols per N-tile
#define BK     32        // fp32 per K-chunk per phase = 1 MFMA k-step
#define KITERS (DIM / BK)   // 32
#define TPE    2         // m-tiles per expert (balanced halves)
#define LROW   40        // shorts per LDS row: 32 bf16 + 8 pad = 80 B (16B-mult)
#define TSZA   (MT * LROW)      // 7680 shorts
#define TSZB   (NTILE * LROW)   // 10240 shorts
#define NXCD   8
#define EPX    (NSESS / NXCD)        // experts per XCD = 4
#define BPE    (TPE * (DIM / NTILE)) // blocks per expert = 8

typedef __attribute__((ext_vector_type(8))) short short8;
typedef __attribute__((ext_vector_type(4))) float floatx4;
typedef __attribute__((ext_vector_type(4))) int intx4;
typedef __attribute__((ext_vector_type(2))) unsigned int uintx2;

// RNE fp32->bf16 for two values, packed into one dword via v_perm_b32.
__device__ __forceinline__ unsigned pack_bf16_2(float fa, float fb) {
  unsigned a = __builtin_bit_cast(unsigned, fa);
  unsigned b = __builtin_bit_cast(unsigned, fb);
  a += 0x7fffu + ((a >> 16) & 1u);
  b += 0x7fffu + ((b >> 16) & 1u);
  return __builtin_amdgcn_perm(b, a, 0x07060302u); // low = bf16(fa), high = bf16(fb)
}

// Round-19 (post-mortem r18: FAILED correctness, absmax 5.15 — pipeline
// prologue bug, not a model failure. PHASE(K) stages chunk K+1 from set
// (K+1)%3 then refills it with chunk K+4; steady state consistent, but the
// prologue only loaded chunks 0/1/2, so PHASE(2) staged STALE chunk-0 data
// as "chunk 3". Fix: LOADSET(xr0, wr0, 3) right after the prologue CVTWRITE
// consumes set0. Induction then gives every PHASE(K) a set holding chunk K+1:
// prologue {3,1,2}; PHASE(K) consumes K+1, reloads K+4 for PHASE(K+3).)
// Theory unchanged from r18: per-CU issued-bytes service rate scales with
// outstanding depth (r13: 10.5 B/cy @192KB in flight; r17: 7.9 @128KB).
//  - MT 192 (balanced split bounds nrows<=192): acc[6][4]=96, wave-tile 96x64
//  - THREE prefetch sets, set == chunk mod 3, issued 3 phases ahead:
//    in-flight ~168 KB/CU (+31% vs r17). Period-6 static unroll (all set
//    indices compile-time; runtime-indexed vec arrays would hit scratch).
//  - shfl-up wave scan + 8-entry cross-wave combine (2 barriers vs 20).
//  - epilogue: r12 coalesced store, max 6 passes, block-uniform early break.
// Est regs ~230 <= 256 (2 waves/SIMD). LDS ~72.5 KB. Canary: WRITE ~32.7MB.
__global__ __launch_bounds__(512, 2) void gemm_kernel(
    const float* __restrict__ x, const float* __restrict__ W,
    const float* __restrict__ bias, const int* __restrict__ sidx,
    float* __restrict__ out)
{
  __shared__ __align__(16) short lds[2 * TSZA + 2 * TSZB]; // 71680 B flat
  __shared__ int row_ids[MT];
  __shared__ int wsum[8];
  short* const As0 = lds;
  short* const As1 = lds + TSZA;
  short* const Bs0 = lds + 2 * TSZA;
  short* const Bs1 = lds + 2 * TSZA + TSZB;

  // ---- XCD-clustered decode ----
  const int hw    = blockIdx.x;          // 0..255, assumed XCD = hw % 8
  const int xcd   = hw & (NXCD - 1);
  const int r     = hw >> 3;             // 0..31: within-XCD sequence
  const int s     = xcd * EPX + (r / BPE);   // expert, clustered per XCD
  const int rr    = r % BPE;             // 0..7
  const int ntile = rr >> 1;             // 0..3 (W slice shared by 2 mtiles)
  const int mtile = rr & 1;
  const int tid   = threadIdx.x;

  const int lane = tid & 63;
  const int wv   = tid >> 6;            // wave id 0..7
  const int wm   = wv >> 2;             // 0..1 : 96-row half
  const int wn   = wv & 3;              // 0..3 : 64-col quarter
  const int fr   = lane & 15;           // fragment row within 16
  const int kg   = lane >> 4;           // fragment k-group (k = kg*8 + j)

  // ---- staging: row = 128 B fp32 = 8 x 16-B chunks; 512 thr -> 64 rows/instr
  const int srw = tid >> 3;             // 0..63 : row within 64-row group
  const int sch = tid & 7;              // 16-B chunk within 128-B k-row

  // B byte-offsets + chunk 0/1/2 B-loads issued before the sidx scan.
  unsigned boff[4];
  floatx4 wr0[4], wr1[4], wr2[4];
  {
    const unsigned wbyte =
        (unsigned)(((size_t)s * DIM * DIM + (size_t)(ntile * NTILE) * DIM) * 4u);
#pragma unroll
    for (int j = 0; j < 4; ++j) {
      const int tr = j * 64 + srw;
      boff[j] = wbyte + (unsigned)((tr * DIM + sch * 4) * 4);
      wr0[j] = *(const floatx4*)((const char*)W + boff[j]);
    }
#pragma unroll
    for (int j = 0; j < 4; ++j)
      wr1[j] = *(const floatx4*)((const char*)W + boff[j] + (BK * 4));
#pragma unroll
    for (int j = 0; j < 4; ++j)
      wr2[j] = *(const floatx4*)((const char*)W + boff[j] + 2 * (BK * 4));
  }

  // ---- ranked compaction via shfl wave-scan (2 barriers total) ----
  const intx4* sv = (const intx4*)(sidx + tid * 16);
  int c = 0;
#pragma unroll
  for (int j = 0; j < 4; ++j) {
    const intx4 v = sv[j];
#pragma unroll
    for (int e = 0; e < 4; ++e) c += (v[e] == s);
  }
  int ic = c;                           // in-wave inclusive prefix
#pragma unroll
  for (int d = 1; d < 64; d <<= 1) {
    const int t = __shfl_up(ic, d);
    if (lane >= d) ic += t;
  }
  if (lane == 63) wsum[wv] = ic;
  __syncthreads();
  int wbase = 0, total = 0;
#pragma unroll
  for (int w = 0; w < 8; ++w) {
    const int v = wsum[w];
    total += v;
    if (w < wv) wbase += v;
  }
  // balanced split: mtile0 -> ranks [0,h), mtile1 -> [h,total); h=ceil(total/2)
  const int h     = (total + 1) >> 1;    // <= 192 for total <= 384 (validated)
  const int lo    = mtile * h;
  const int hi    = mtile ? total : h;
  const int nrows = hi - lo;
  if (nrows == 0) return;               // uniform across block
  const int base_rank = wbase + ic - c; // exclusive global prefix

  if (tid < MT) row_ids[tid] = -1;
  __syncthreads();
  {
    int r2 = base_rank;
#pragma unroll
    for (int j = 0; j < 4; ++j) {
      const intx4 v = sv[j];
#pragma unroll
      for (int e = 0; e < 4; ++e) {
        if (v[e] == s) {
          if (r2 >= lo && r2 < hi) row_ids[r2 - lo] = tid * 16 + 4 * j + e;
          ++r2;
        }
      }
    }
  }
  __syncthreads();

  unsigned aoff[3];
  floatx4 xr0[3], xr1[3], xr2[3];
#pragma unroll
  for (int j = 0; j < 3; ++j) {
    int ar = row_ids[j * 64 + srw];
    if (ar < 0) ar = 0;                 // finite dummy; epilogue masks rows >= nrows
    aoff[j] = (unsigned)((ar * DIM + sch * 4) * 4);
    xr0[j] = *(const floatx4*)((const char*)x + aoff[j]);                 // k0
  }
#pragma unroll
  for (int j = 0; j < 3; ++j)
    xr1[j] = *(const floatx4*)((const char*)x + aoff[j] + (BK * 4));      // k1
#pragma unroll
  for (int j = 0; j < 3; ++j)
    xr2[j] = *(const floatx4*)((const char*)x + aoff[j] + 2 * (BK * 4));  // k2

  floatx4 acc[6][4] = {};

#define LOADSET(XR, WR, KB)                                                    \
  {                                                                            \
    _Pragma("unroll")                                                          \
    for (int j = 0; j < 3; ++j)                                                \
      XR[j] = *(const floatx4*)((const char*)x + aoff[j] + (KB) * (BK * 4));   \
    _Pragma("unroll")                                                          \
    for (int j = 0; j < 4; ++j)                                                \
      WR[j] = *(const floatx4*)((const char*)W + boff[j] + (KB) * (BK * 4));   \
  }

#define CVTWRITE(XR, WR, AS, BS)                                               \
  {                                                                            \
    _Pragma("unroll")                                                          \
    for (int j = 0; j < 3; ++j) {                                              \
      const int off = (j * 64 + srw) * LROW + sch * 4;                         \
      uintx2 ua = { pack_bf16_2(XR[j][0], XR[j][1]),                           \
                    pack_bf16_2(XR[j][2], XR[j][3]) };                         \
      *(uintx2*)&AS[off] = ua;                                                 \
    }                                                                          \
    _Pragma("unroll")                                                          \
    for (int j = 0; j < 4; ++j) {                                              \
      const int off = (j * 64 + srw) * LROW + sch * 4;                         \
      uintx2 ub = { pack_bf16_2(WR[j][0], WR[j][1]),                           \
                    pack_bf16_2(WR[j][2], WR[j][3]) };                         \
      *(uintx2*)&BS[off] = ub;                                                 \
    }                                                                          \
  }

#define COMPUTE(AS, BS)                                                        \
  {                                                                            \
    short8 fb[4];                                                              \
    _Pragma("unroll")                                                          \
    for (int i = 0; i < 4; ++i)                                                \
      fb[i] = *(const short8*)&BS[(wn * 64 + i * 16 + fr) * LROW + kg * 8];    \
    _Pragma("unroll")                                                          \
    for (int mi = 0; mi < 6; ++mi) {                                           \
      const short8 fa = *(const short8*)&AS[(wm * 96 + mi * 16 + fr) * LROW + kg * 8]; \
      _Pragma("unroll")                                                        \
      for (int ni = 0; ni < 4; ++ni)                                           \
        acc[mi][ni] = __builtin_amdgcn_mfma_f32_16x16x32_bf16(                 \
            fa, fb[ni], acc[mi][ni], 0, 0, 0);                                 \
    }                                                                          \
  }

  // phase K: compute chunk K from LDS[K&1]; stage set (K+1)%3 (chunk K+1)
  // into LDS[(K+1)&1]; refill that set with chunk K+4; barrier. Static
  // indices via period-6 expansion.
#define PHASE(K, CUR, NXT, XR, WR)                                             \
  {                                                                            \
    COMPUTE(As##CUR, Bs##CUR);                                                 \
    if ((K) + 1 < KITERS) CVTWRITE(XR, WR, As##NXT, Bs##NXT);                  \
    if ((K) + 4 < KITERS) LOADSET(XR, WR, (K) + 4);                            \
    __syncthreads();                                                           \
  }

  // prologue: chunk 0 (set0) -> LDS0; then REFILL set0 with chunk 3 (the r18
  // bug: PHASE(2) stages chunk 3 from set0 — without this it staged stale
  // chunk-0 data). Sets then hold {3,1,2} entering the loop.
  CVTWRITE(xr0, wr0, As0, Bs0);
  LOADSET(xr0, wr0, 3);
  __syncthreads();

  PHASE( 0, 0, 1, xr1, wr1)  PHASE( 1, 1, 0, xr2, wr2)  PHASE( 2, 0, 1, xr0, wr0)
  PHASE( 3, 1, 0, xr1, wr1)  PHASE( 4, 0, 1, xr2, wr2)  PHASE( 5, 1, 0, xr0, wr0)
  PHASE( 6, 0, 1, xr1, wr1)  PHASE( 7, 1, 0, xr2, wr2)  PHASE( 8, 0, 1, xr0, wr0)
  PHASE( 9, 1, 0, xr1, wr1)  PHASE(10, 0, 1, xr2, wr2)  PHASE(11, 1, 0, xr0, wr0)
  PHASE(12, 0, 1, xr1, wr1)  PHASE(13, 1, 0, xr2, wr2)  PHASE(14, 0, 1, xr0, wr0)
  PHASE(15, 1, 0, xr1, wr1)  PHASE(16, 0, 1, xr2, wr2)  PHASE(17, 1, 0, xr0, wr0)
  PHASE(18, 0, 1, xr1, wr1)  PHASE(19, 1, 0, xr2, wr2)  PHASE(20, 0, 1, xr0, wr0)
  PHASE(21, 1, 0, xr1, wr1)  PHASE(22, 0, 1, xr2, wr2)  PHASE(23, 1, 0, xr0, wr0)
  PHASE(24, 0, 1, xr1, wr1)  PHASE(25, 1, 0, xr2, wr2)  PHASE(26, 0, 1, xr0, wr0)
  PHASE(27, 1, 0, xr1, wr1)  PHASE(28, 0, 1, xr2, wr2)  PHASE(29, 1, 0, xr0, wr0)
  PHASE(30, 0, 1, xr1, wr1)  PHASE(31, 1, 0, xr2, wr2)

#undef PHASE
#undef LOADSET
#undef CVTWRITE
#undef COMPUTE

  // ---- coalesced epilogue (r12; 192 rows -> up to 6 passes of 32) ---------
  // acc: tile row = wm*96 + mi*16 + kg*4 + q, col = wn*64 + ni*16 + fr.
  // Pass p: rows [32p,32p+32) via [32][260] f32 aliased onto lds (33280 B).
  // One dwordx4 store = 64 lanes x 16 B = FULL 1-KB output row. Early break
  // when the window is beyond nrows (block-uniform).
  float* obuf = (float*)lds;
  const int col0 = ntile * NTILE + wn * 64;
  float bv[4];
#pragma unroll
  for (int ni = 0; ni < 4; ++ni) bv[ni] = bias[s * DIM + col0 + ni * 16 + fr];

  const int rbase = tid >> 6;          // 0..7 : row within 8-row store group
  const int ch    = tid & 63;          // 16-B chunk within 1-KB row

#pragma unroll
  for (int p = 0; p < 6; ++p) {
    if (p * 32 >= nrows) break;        // block-uniform: no divergence
    if (wm == (p >= 3 ? 1 : 0)) {
#pragma unroll
      for (int mh = 0; mh < 2; ++mh) {
        const int mi = (p % 3) * 2 + mh;
        const int lr = mi * 16 + kg * 4 - (p % 3) * 32;   // 0..28 local row base
#pragma unroll
        for (int q = 0; q < 4; ++q)
#pragma unroll
          for (int ni = 0; ni < 4; ++ni)
            obuf[(lr + q) * 260 + wn * 64 + ni * 16 + fr] = acc[mi][ni][q] + bv[ni];
      }
    }
    __syncthreads();
#pragma unroll
    for (int j = 0; j < 4; ++j) {
      const int lr = j * 8 + rbase;              // 0..31
      const int ml = p * 32 + lr;                // tile row
      if (ml < nrows) {
        const int orow = row_ids[ml];
        const floatx4 v = *(const floatx4*)&obuf[lr * 260 + ch * 4];
        *(floatx4*)&out[(size_t)orow * DIM + ntile * NTILE + ch * 4] = v;
      }
    }
    __syncthreads();
  }
}

extern "C" void kernel_launch(void* const* d_in, const int* in_sizes, int n_in,
                              void* d_out, int out_size, void* d_ws, size_t ws_size,
                              hipStream_t stream) {
  const float* x    = (const float*)d_in[0];
  const float* W    = (const float*)d_in[1];
  const float* b    = (const float*)d_in[2];
  const int*   sidx = (const int*)d_in[3];
  float* out = (float*)d_out;
  (void)d_ws; (void)ws_size;  // OFF-LIMITS: any ws touch => 512MiB re-poison
                              // fill (~80us) per iteration (r9 post-mortem)

  hipLaunchKernelGGL(gemm_kernel, dim3(NSESS * TPE * (DIM / NTILE)), dim3(512),
                     0, stream, x, W, b, sidx, out);
}